// Round 1
// baseline (280.134 us; speedup 1.0000x reference)
//
#include <hip/hip_runtime.h>
#include <hip/hip_bf16.h>

typedef float f32x4 __attribute__((ext_vector_type(4)));
typedef __bf16 bf16x8 __attribute__((ext_vector_type(8)));
typedef __bf16 bf16x4 __attribute__((ext_vector_type(4)));

#define D_MODEL 1024
#define T_SEQ   2048
#define NH      16
#define HD      64

// ---------------------------------------------------------------------------
// Kernel 0: RoPE table  tab[t][i] = (cos(t*inv_freq_i), sin(t*inv_freq_i)), i<32
// ---------------------------------------------------------------------------
__global__ __launch_bounds__(256) void k_rope_table(float2* __restrict__ tab) {
    int idx = blockIdx.x * 256 + threadIdx.x;     // 65536 = 2048*32
    int t = idx >> 5, i = idx & 31;
    float inv = powf(10000.f, -(float)i * (1.f / 32.f));
    float ang = (float)t * inv;
    tab[idx] = make_float2(cosf(ang), sinf(ang));
}

// ---------------------------------------------------------------------------
// Kernel 1: RMSNorm + cast to bf16.  One block per row of 1024.
// ---------------------------------------------------------------------------
__global__ __launch_bounds__(256) void k_rmsnorm(const float* __restrict__ x,
                                                 const float* __restrict__ w,
                                                 __bf16* __restrict__ h) {
    int row = blockIdx.x;
    int tid = threadIdx.x;
    const float4 v = ((const float4*)(x + (size_t)row * D_MODEL))[tid];
    float ss = v.x * v.x + v.y * v.y + v.z * v.z + v.w * v.w;
#pragma unroll
    for (int off = 32; off > 0; off >>= 1) ss += __shfl_down(ss, off, 64);
    __shared__ float red[4];
    if ((tid & 63) == 0) red[tid >> 6] = ss;
    __syncthreads();
    float total = red[0] + red[1] + red[2] + red[3];
    float rms = rsqrtf(total * (1.f / 1024.f) + 1e-5f);
    const float4 wv = ((const float4*)w)[tid];
    bf16x4 o;
    o[0] = (__bf16)(v.x * rms * wv.x);
    o[1] = (__bf16)(v.y * rms * wv.y);
    o[2] = (__bf16)(v.z * rms * wv.z);
    o[3] = (__bf16)(v.w * rms * wv.w);
    ((bf16x4*)(h + (size_t)row * D_MODEL))[tid] = o;
}

// ---------------------------------------------------------------------------
// Kernel 2: transpose + cast f32[R][C] -> bf16[C][R]
// ---------------------------------------------------------------------------
__global__ __launch_bounds__(256) void k_transpose_cast(const float* __restrict__ src,
                                                        __bf16* __restrict__ dst,
                                                        int R, int C) {
    __shared__ float tile[32][33];
    int tx = threadIdx.x & 31, ty = threadIdx.x >> 5;   // ty 0..7
    int c0 = blockIdx.x * 32, r0 = blockIdx.y * 32;
#pragma unroll
    for (int dy = 0; dy < 32; dy += 8)
        tile[ty + dy][tx] = src[(size_t)(r0 + ty + dy) * C + c0 + tx];
    __syncthreads();
#pragma unroll
    for (int dy = 0; dy < 32; dy += 8)
        dst[(size_t)(c0 + ty + dy) * R + r0 + tx] = (__bf16)tile[tx][ty + dy];
}

// ---------------------------------------------------------------------------
// Kernel 3/5: 128x128 bf16 MFMA GEMM.  A[M][K] bf16 row-major, Bt[N][K] bf16.
// EPI==0: qkv epilogue (RoPE on Q/K -> Qr/Kr [b][h][t][d]; V -> Vt [b][h][d][t])
// EPI==1: out = resid + A@B  (f32)
// ---------------------------------------------------------------------------
template <int EPI>
__global__ __launch_bounds__(256) void k_gemm(const __bf16* __restrict__ A,
                                              const __bf16* __restrict__ Bt, int K,
                                              const float2* __restrict__ tab,
                                              __bf16* __restrict__ Qr,
                                              __bf16* __restrict__ Kr,
                                              __bf16* __restrict__ Vt,
                                              const float* __restrict__ resid,
                                              float* __restrict__ outf) {
    __shared__ __bf16 ldsA[128 * 64];
    __shared__ __bf16 ldsB[128 * 64];
    const int tid  = threadIdx.x;
    const int lane = tid & 63;
    const int wave = tid >> 6;
    const int tile_m = blockIdx.y * 128;
    const int tile_n = blockIdx.x * 128;
    const int wm = (wave >> 1) * 64;
    const int wn = (wave & 1) * 64;
    f32x4 acc[4][4] = {};

    const int srow = tid >> 3;   // 0..31 (+ i*32)
    const int ssl  = tid & 7;    // 16B slot along K (8 slots of 8 bf16)

    for (int k0 = 0; k0 < K; k0 += 64) {
#pragma unroll
        for (int i = 0; i < 4; i++) {
            int row = i * 32 + srow;
            uint4 va = *(const uint4*)(A  + (size_t)(tile_m + row) * K + k0 + ssl * 8);
            uint4 vb = *(const uint4*)(Bt + (size_t)(tile_n + row) * K + k0 + ssl * 8);
            *(uint4*)((char*)ldsA + row * 128 + ((ssl ^ (row & 7)) << 4)) = va;
            *(uint4*)((char*)ldsB + row * 128 + ((ssl ^ (row & 7)) << 4)) = vb;
        }
        __syncthreads();
#pragma unroll
        for (int kc = 0; kc < 2; kc++) {
            bf16x8 af[4], bfr[4];
            int s = kc * 4 + (lane >> 4);
#pragma unroll
            for (int mi = 0; mi < 4; mi++) {
                int row = wm + mi * 16 + (lane & 15);
                af[mi] = *(const bf16x8*)((char*)ldsA + row * 128 + ((s ^ (row & 7)) << 4));
            }
#pragma unroll
            for (int nf = 0; nf < 4; nf++) {
                int row = wn + nf * 16 + (lane & 15);
                bfr[nf] = *(const bf16x8*)((char*)ldsB + row * 128 + ((s ^ (row & 7)) << 4));
            }
#pragma unroll
            for (int mi = 0; mi < 4; mi++)
#pragma unroll
                for (int nf = 0; nf < 4; nf++)
                    acc[mi][nf] = __builtin_amdgcn_mfma_f32_16x16x32_bf16(
                        af[mi], bfr[nf], acc[mi][nf], 0, 0, 0);
        }
        __syncthreads();
    }

    if (EPI == 0) {
        const int nb  = tile_n + wn;          // 64-aligned -> one head, one section
        const int sec = nb >> 10;             // 0=Q 1=K 2=V
        const int hh  = (nb & 1023) >> 6;
        if (sec < 2) {
            __bf16* dstbase = (sec == 0) ? Qr : Kr;
            const float sc = (sec == 0) ? 0.125f : 1.0f;   // fold HEAD_DIM^-0.5 into Q
#pragma unroll
            for (int mi = 0; mi < 4; mi++) {
#pragma unroll
                for (int r = 0; r < 4; r++) {
                    int m = tile_m + wm + mi * 16 + (lane >> 4) * 4 + r;
                    int bb = m >> 11, t = m & 2047;
                    float2 cs0 = tab[t * 32 + (lane & 15)];
                    float2 cs1 = tab[t * 32 + 16 + (lane & 15)];
                    float x0 = acc[mi][0][r], x1 = acc[mi][1][r];
                    float x2 = acc[mi][2][r], x3 = acc[mi][3][r];
                    __bf16* dst = dstbase + ((size_t)(bb * NH + hh) * T_SEQ + t) * HD + (lane & 15);
                    dst[0]  = (__bf16)((x0 * cs0.x - x2 * cs0.y) * sc);
                    dst[16] = (__bf16)((x1 * cs1.x - x3 * cs1.y) * sc);
                    dst[32] = (__bf16)((x2 * cs0.x + x0 * cs0.y) * sc);
                    dst[48] = (__bf16)((x3 * cs1.x + x1 * cs1.y) * sc);
                }
            }
        } else {
#pragma unroll
            for (int mi = 0; mi < 4; mi++) {
                int m0 = tile_m + wm + mi * 16 + (lane >> 4) * 4;
                int bb = m0 >> 11, t0 = m0 & 2047;
#pragma unroll
                for (int nf = 0; nf < 4; nf++) {
                    int d = nf * 16 + (lane & 15);
                    bf16x4 pv;
                    pv[0] = (__bf16)acc[mi][nf][0];
                    pv[1] = (__bf16)acc[mi][nf][1];
                    pv[2] = (__bf16)acc[mi][nf][2];
                    pv[3] = (__bf16)acc[mi][nf][3];
                    *(bf16x4*)(Vt + ((size_t)(bb * NH + hh) * HD + d) * T_SEQ + t0) = pv;
                }
            }
        }
    } else {
#pragma unroll
        for (int mi = 0; mi < 4; mi++)
#pragma unroll
            for (int r = 0; r < 4; r++) {
                int m = tile_m + wm + mi * 16 + (lane >> 4) * 4 + r;
#pragma unroll
                for (int nf = 0; nf < 4; nf++) {
                    int n = tile_n + wn + nf * 16 + (lane & 15);
                    size_t idx = (size_t)m * D_MODEL + n;
                    outf[idx] = resid[idx] + acc[mi][nf][r];
                }
            }
    }
}

// ---------------------------------------------------------------------------
// Kernel 4: bidirectional flash attention.
// grid (16 q-tiles, 32 bh).  4 independent waves, 32 q-rows each, no barriers.
// Q pre-scaled by 0.125.  Qr/Kr: [b][h][t][d]; Vt: [b][h][d][t].
// ---------------------------------------------------------------------------
__global__ __launch_bounds__(256) void k_attn(const __bf16* __restrict__ Qr,
                                              const __bf16* __restrict__ Kr,
                                              const __bf16* __restrict__ Vt,
                                              __bf16* __restrict__ aout) {
    __shared__ __bf16 plds_all[4][32 * 64];
    const int lane = threadIdx.x & 63;
    const int wave = threadIdx.x >> 6;
    const int bh = blockIdx.y;
    const int q0 = blockIdx.x * 128 + wave * 32;
    const __bf16* Q  = Qr + (size_t)bh * T_SEQ * HD;
    const __bf16* Kp = Kr + (size_t)bh * T_SEQ * HD;
    const __bf16* Vp = Vt + (size_t)bh * HD * T_SEQ;
    __bf16* plds = plds_all[wave];

    bf16x8 qf[2][2];
#pragma unroll
    for (int mi = 0; mi < 2; mi++)
#pragma unroll
        for (int kc = 0; kc < 2; kc++)
            qf[mi][kc] = *(const bf16x8*)(Q + (size_t)(q0 + mi * 16 + (lane & 15)) * HD +
                                          kc * 32 + (lane >> 4) * 8);

    f32x4 o[2][4] = {};
    float mrun[2][4], lrun[2][4];
#pragma unroll
    for (int mi = 0; mi < 2; mi++)
#pragma unroll
        for (int r = 0; r < 4; r++) { mrun[mi][r] = -1e30f; lrun[mi][r] = 0.f; }

    for (int kk = 0; kk < T_SEQ; kk += 64) {
        f32x4 s[2][4] = {};
#pragma unroll
        for (int kc = 0; kc < 2; kc++) {
            bf16x8 kf[4];
#pragma unroll
            for (int nf = 0; nf < 4; nf++)
                kf[nf] = *(const bf16x8*)(Kp + (size_t)(kk + nf * 16 + (lane & 15)) * HD +
                                          kc * 32 + (lane >> 4) * 8);
#pragma unroll
            for (int mi = 0; mi < 2; mi++)
#pragma unroll
                for (int nf = 0; nf < 4; nf++)
                    s[mi][nf] = __builtin_amdgcn_mfma_f32_16x16x32_bf16(
                        qf[mi][kc], kf[nf], s[mi][nf], 0, 0, 0);
        }
        // online softmax, rows are wave-local; stats per lane for its 4 rows
#pragma unroll
        for (int mi = 0; mi < 2; mi++) {
            float tv[4], fac[4];
#pragma unroll
            for (int r = 0; r < 4; r++)
                tv[r] = fmaxf(fmaxf(s[mi][0][r], s[mi][1][r]),
                              fmaxf(s[mi][2][r], s[mi][3][r]));
#pragma unroll
            for (int d = 1; d < 16; d <<= 1)
#pragma unroll
                for (int r = 0; r < 4; r++)
                    tv[r] = fmaxf(tv[r], __shfl_xor(tv[r], d, 64));
#pragma unroll
            for (int r = 0; r < 4; r++) {
                float mnew = fmaxf(mrun[mi][r], tv[r]);
                fac[r] = __expf(mrun[mi][r] - mnew);
                mrun[mi][r] = mnew;
            }
            float ts[4] = {0.f, 0.f, 0.f, 0.f};
#pragma unroll
            for (int nf = 0; nf < 4; nf++)
#pragma unroll
                for (int r = 0; r < 4; r++) {
                    float p = __expf(s[mi][nf][r] - mrun[mi][r]);
                    ts[r] += p;
                    int row = mi * 16 + (lane >> 4) * 4 + r;
                    int colb = (nf * 16 + (lane & 15)) * 2;
                    *(__bf16*)((char*)plds + row * 128 + (colb ^ ((row & 7) << 4))) = (__bf16)p;
                }
#pragma unroll
            for (int d = 1; d < 16; d <<= 1)
#pragma unroll
                for (int r = 0; r < 4; r++)
                    ts[r] += __shfl_xor(ts[r], d, 64);
#pragma unroll
            for (int r = 0; r < 4; r++)
                lrun[mi][r] = lrun[mi][r] * fac[r] + ts[r];
#pragma unroll
            for (int nf = 0; nf < 4; nf++)
#pragma unroll
                for (int r = 0; r < 4; r++)
                    o[mi][nf][r] *= fac[r];
        }
        // PV: A = P (from wave-private LDS), B = V via Vt (contiguous 16B)
#pragma unroll
        for (int kc = 0; kc < 2; kc++) {
            bf16x8 pf[2], vf[4];
            int sslot = kc * 4 + (lane >> 4);
#pragma unroll
            for (int mi = 0; mi < 2; mi++) {
                int row = mi * 16 + (lane & 15);
                pf[mi] = *(const bf16x8*)((char*)plds + row * 128 + ((sslot ^ (row & 7)) << 4));
            }
#pragma unroll
            for (int nf = 0; nf < 4; nf++)
                vf[nf] = *(const bf16x8*)(Vp + (size_t)(nf * 16 + (lane & 15)) * T_SEQ +
                                          kk + kc * 32 + (lane >> 4) * 8);
#pragma unroll
            for (int mi = 0; mi < 2; mi++)
#pragma unroll
                for (int nf = 0; nf < 4; nf++)
                    o[mi][nf] = __builtin_amdgcn_mfma_f32_16x16x32_bf16(
                        pf[mi], vf[nf], o[mi][nf], 0, 0, 0);
        }
    }

    const int bb = bh >> 4, hh = bh & 15;
#pragma unroll
    for (int mi = 0; mi < 2; mi++)
#pragma unroll
        for (int r = 0; r < 4; r++) {
            int t = q0 + mi * 16 + (lane >> 4) * 4 + r;
            float inv = 1.f / lrun[mi][r];
#pragma unroll
            for (int nf = 0; nf < 4; nf++) {
                int d = nf * 16 + (lane & 15);
                aout[((size_t)(bb * T_SEQ + t)) * D_MODEL + hh * HD + d] =
                    (__bf16)(o[mi][nf][r] * inv);
            }
        }
}

// ---------------------------------------------------------------------------
extern "C" void kernel_launch(void* const* d_in, const int* in_sizes, int n_in,
                              void* d_out, int out_size, void* d_ws, size_t ws_size,
                              hipStream_t stream) {
    const float* x      = (const float*)d_in[0];
    const float* norm_w = (const float*)d_in[1];
    const float* w_qkv  = (const float*)d_in[2];
    const float* w_out  = (const float*)d_in[3];
    float* out = (float*)d_out;
    char* ws = (char*)d_ws;

    // workspace layout (41 MB)
    __bf16* hbuf  = (__bf16*)(ws);                              // 8 MB (reused as attn_out)
    __bf16* wqkvT = (__bf16*)(ws + ((size_t)8  << 20));         // 6 MB
    __bf16* woutT = (__bf16*)(ws + ((size_t)14 << 20));         // 2 MB
    float2* tab   = (float2*)(ws + ((size_t)16 << 20));         // 0.5 MB
    __bf16* Qr    = (__bf16*)(ws + ((size_t)17 << 20));         // 8 MB
    __bf16* Kr    = (__bf16*)(ws + ((size_t)25 << 20));         // 8 MB
    __bf16* Vt    = (__bf16*)(ws + ((size_t)33 << 20));         // 8 MB

    k_rope_table<<<dim3(256), dim3(256), 0, stream>>>(tab);
    k_rmsnorm<<<dim3(4096), dim3(256), 0, stream>>>(x, norm_w, hbuf);
    k_transpose_cast<<<dim3(96, 32), dim3(256), 0, stream>>>(w_qkv, wqkvT, 1024, 3072);
    k_transpose_cast<<<dim3(32, 32), dim3(256), 0, stream>>>(w_out, woutT, 1024, 1024);
    k_gemm<0><<<dim3(24, 32), dim3(256), 0, stream>>>(hbuf, wqkvT, 1024, tab,
                                                      Qr, Kr, Vt, nullptr, nullptr);
    k_attn<<<dim3(16, 32), dim3(256), 0, stream>>>(Qr, Kr, Vt, hbuf);
    k_gemm<1><<<dim3(8, 32), dim3(256), 0, stream>>>(hbuf, woutT, 1024, nullptr,
                                                     nullptr, nullptr, nullptr, x, out);
}

// Round 2
// 274.313 us; speedup vs baseline: 1.0212x; 1.0212x over previous
//
#include <hip/hip_runtime.h>
#include <hip/hip_bf16.h>

typedef float f32x4 __attribute__((ext_vector_type(4)));
typedef __bf16 bf16x8 __attribute__((ext_vector_type(8)));
typedef __bf16 bf16x4 __attribute__((ext_vector_type(4)));

#define D_MODEL 1024
#define T_SEQ   2048
#define NH      16
#define HD      64

// async global->LDS, 16B per lane.  LDS dest must be wave-uniform base; HW
// writes base + lane*16.
__device__ __forceinline__ void gload16(const void* g, void* l) {
    __builtin_amdgcn_global_load_lds(
        (const __attribute__((address_space(1))) unsigned int*)g,
        (__attribute__((address_space(3))) unsigned int*)l, 16, 0, 0);
}

// ---------------------------------------------------------------------------
// Kernel 0: RoPE table  tab[t][i] = (cos(t*inv_freq_i), sin(t*inv_freq_i)), i<32
// ---------------------------------------------------------------------------
__global__ __launch_bounds__(256) void k_rope_table(float2* __restrict__ tab) {
    int idx = blockIdx.x * 256 + threadIdx.x;     // 65536 = 2048*32
    int t = idx >> 5, i = idx & 31;
    float inv = powf(10000.f, -(float)i * (1.f / 32.f));
    float ang = (float)t * inv;
    tab[idx] = make_float2(cosf(ang), sinf(ang));
}

// ---------------------------------------------------------------------------
// Kernel 1: RMSNorm + cast to bf16.  One block per row of 1024.
// ---------------------------------------------------------------------------
__global__ __launch_bounds__(256) void k_rmsnorm(const float* __restrict__ x,
                                                 const float* __restrict__ w,
                                                 __bf16* __restrict__ h) {
    int row = blockIdx.x;
    int tid = threadIdx.x;
    const float4 v = ((const float4*)(x + (size_t)row * D_MODEL))[tid];
    float ss = v.x * v.x + v.y * v.y + v.z * v.z + v.w * v.w;
#pragma unroll
    for (int off = 32; off > 0; off >>= 1) ss += __shfl_down(ss, off, 64);
    __shared__ float red[4];
    if ((tid & 63) == 0) red[tid >> 6] = ss;
    __syncthreads();
    float total = red[0] + red[1] + red[2] + red[3];
    float rms = rsqrtf(total * (1.f / 1024.f) + 1e-5f);
    const float4 wv = ((const float4*)w)[tid];
    bf16x4 o;
    o[0] = (__bf16)(v.x * rms * wv.x);
    o[1] = (__bf16)(v.y * rms * wv.y);
    o[2] = (__bf16)(v.z * rms * wv.z);
    o[3] = (__bf16)(v.w * rms * wv.w);
    ((bf16x4*)(h + (size_t)row * D_MODEL))[tid] = o;
}

// ---------------------------------------------------------------------------
// Kernel 2: transpose + cast f32[R][C] -> bf16[C][R]
// ---------------------------------------------------------------------------
__global__ __launch_bounds__(256) void k_transpose_cast(const float* __restrict__ src,
                                                        __bf16* __restrict__ dst,
                                                        int R, int C) {
    __shared__ float tile[32][33];
    int tx = threadIdx.x & 31, ty = threadIdx.x >> 5;   // ty 0..7
    int c0 = blockIdx.x * 32, r0 = blockIdx.y * 32;
#pragma unroll
    for (int dy = 0; dy < 32; dy += 8)
        tile[ty + dy][tx] = src[(size_t)(r0 + ty + dy) * C + c0 + tx];
    __syncthreads();
#pragma unroll
    for (int dy = 0; dy < 32; dy += 8)
        dst[(size_t)(c0 + ty + dy) * R + r0 + tx] = (__bf16)tile[tx][ty + dy];
}

// ---------------------------------------------------------------------------
// Kernel 3/5: 128x128 bf16 MFMA GEMM.  A[M][K] bf16 row-major, Bt[N][K] bf16.
// Staging via global_load_lds (16B) with pre-swizzled global source so the
// linear LDS write order lands in the XOR-swizzled layout the reads expect.
// EPI==0: qkv epilogue (RoPE on Q/K -> Qr/Kr [b][h][t][d]; V -> Vt [b][h][d][t])
// EPI==1: out = resid + A@B  (f32)
// ---------------------------------------------------------------------------
template <int EPI>
__global__ __launch_bounds__(256) void k_gemm(const __bf16* __restrict__ A,
                                              const __bf16* __restrict__ Bt, int K,
                                              const float2* __restrict__ tab,
                                              __bf16* __restrict__ Qr,
                                              __bf16* __restrict__ Kr,
                                              __bf16* __restrict__ Vt,
                                              const float* __restrict__ resid,
                                              float* __restrict__ outf) {
    __shared__ __bf16 ldsA[128 * 64];
    __shared__ __bf16 ldsB[128 * 64];
    const int tid  = threadIdx.x;
    const int lane = tid & 63;
    const int wave = tid >> 6;
    const int tile_m = blockIdx.y * 128;
    const int tile_n = blockIdx.x * 128;
    const int wm = (wave >> 1) * 64;
    const int wn = (wave & 1) * 64;
    f32x4 acc[4][4] = {};

    const int srow8 = lane >> 3;   // row within wave's 8-row stripe
    const int sslot = lane & 7;    // linear 16B slot this lane WRITES

    for (int k0 = 0; k0 < K; k0 += 64) {
#pragma unroll
        for (int i = 0; i < 4; i++) {
            int rbase = i * 32 + wave * 8;
            int row = rbase + srow8;
            int scol = (sslot ^ (row & 7)) * 8;   // pre-swizzled source slot
            gload16(A  + (size_t)(tile_m + row) * K + k0 + scol,
                    (char*)ldsA + rbase * 128);
            gload16(Bt + (size_t)(tile_n + row) * K + k0 + scol,
                    (char*)ldsB + rbase * 128);
        }
        __syncthreads();
#pragma unroll
        for (int kc = 0; kc < 2; kc++) {
            bf16x8 af[4], bfr[4];
            int s = kc * 4 + (lane >> 4);
#pragma unroll
            for (int mi = 0; mi < 4; mi++) {
                int row = wm + mi * 16 + (lane & 15);
                af[mi] = *(const bf16x8*)((char*)ldsA + row * 128 + ((s ^ (row & 7)) << 4));
            }
#pragma unroll
            for (int nf = 0; nf < 4; nf++) {
                int row = wn + nf * 16 + (lane & 15);
                bfr[nf] = *(const bf16x8*)((char*)ldsB + row * 128 + ((s ^ (row & 7)) << 4));
            }
#pragma unroll
            for (int mi = 0; mi < 4; mi++)
#pragma unroll
                for (int nf = 0; nf < 4; nf++)
                    acc[mi][nf] = __builtin_amdgcn_mfma_f32_16x16x32_bf16(
                        af[mi], bfr[nf], acc[mi][nf], 0, 0, 0);
        }
        __syncthreads();
    }

    if (EPI == 0) {
        const int nb  = tile_n + wn;          // 64-aligned -> one head, one section
        const int sec = nb >> 10;             // 0=Q 1=K 2=V
        const int hh  = (nb & 1023) >> 6;
        if (sec < 2) {
            __bf16* dstbase = (sec == 0) ? Qr : Kr;
            // fold HEAD_DIM^-0.5 * log2(e) into Q so attention works in exp2 domain
            const float sc = (sec == 0) ? 0.180336880111f : 1.0f;
#pragma unroll
            for (int mi = 0; mi < 4; mi++) {
#pragma unroll
                for (int r = 0; r < 4; r++) {
                    int m = tile_m + wm + mi * 16 + (lane >> 4) * 4 + r;
                    int bb = m >> 11, t = m & 2047;
                    float2 cs0 = tab[t * 32 + (lane & 15)];
                    float2 cs1 = tab[t * 32 + 16 + (lane & 15)];
                    float x0 = acc[mi][0][r], x1 = acc[mi][1][r];
                    float x2 = acc[mi][2][r], x3 = acc[mi][3][r];
                    __bf16* dst = dstbase + ((size_t)(bb * NH + hh) * T_SEQ + t) * HD + (lane & 15);
                    dst[0]  = (__bf16)((x0 * cs0.x - x2 * cs0.y) * sc);
                    dst[16] = (__bf16)((x1 * cs1.x - x3 * cs1.y) * sc);
                    dst[32] = (__bf16)((x2 * cs0.x + x0 * cs0.y) * sc);
                    dst[48] = (__bf16)((x3 * cs1.x + x1 * cs1.y) * sc);
                }
            }
        } else {
#pragma unroll
            for (int mi = 0; mi < 4; mi++) {
                int m0 = tile_m + wm + mi * 16 + (lane >> 4) * 4;
                int bb = m0 >> 11, t0 = m0 & 2047;
#pragma unroll
                for (int nf = 0; nf < 4; nf++) {
                    int d = nf * 16 + (lane & 15);
                    bf16x4 pv;
                    pv[0] = (__bf16)acc[mi][nf][0];
                    pv[1] = (__bf16)acc[mi][nf][1];
                    pv[2] = (__bf16)acc[mi][nf][2];
                    pv[3] = (__bf16)acc[mi][nf][3];
                    *(bf16x4*)(Vt + ((size_t)(bb * NH + hh) * HD + d) * T_SEQ + t0) = pv;
                }
            }
        }
    } else {
#pragma unroll
        for (int mi = 0; mi < 4; mi++)
#pragma unroll
            for (int r = 0; r < 4; r++) {
                int m = tile_m + wm + mi * 16 + (lane >> 4) * 4 + r;
#pragma unroll
                for (int nf = 0; nf < 4; nf++) {
                    int n = tile_n + wn + nf * 16 + (lane & 15);
                    size_t idx = (size_t)m * D_MODEL + n;
                    outf[idx] = resid[idx] + acc[mi][nf][r];
                }
            }
    }
}

// ---------------------------------------------------------------------------
// Kernel 4: bidirectional flash attention, swapped-QK^T form.
// grid (16 q-tiles, 32 bh).  4 independent waves, 32 q-rows each, no barriers.
// S^T = mfma(K, Q): lane owns q = qi*16 + (lane&15), k = ki*16 + (lane>>4)*4 + r
// -> softmax row-reduce is in-lane over 16 values + 2 shfl_xor levels.
// Q pre-scaled by 0.125*log2e; softmax in exp2 domain.
// Qr/Kr: [b][h][t][d]; Vt: [b][h][d][t].
// ---------------------------------------------------------------------------
__global__ __launch_bounds__(256) void k_attn(const __bf16* __restrict__ Qr,
                                              const __bf16* __restrict__ Kr,
                                              const __bf16* __restrict__ Vt,
                                              __bf16* __restrict__ aout) {
    __shared__ __bf16 plds_all[4][32 * 64];
    const int lane = threadIdx.x & 63;
    const int wave = threadIdx.x >> 6;
    const int g  = lane >> 4;     // lane group 0..3
    const int lr = lane & 15;
    const int bh = blockIdx.y;
    const int q0 = blockIdx.x * 128 + wave * 32;
    const __bf16* Q  = Qr + (size_t)bh * T_SEQ * HD;
    const __bf16* Kp = Kr + (size_t)bh * T_SEQ * HD;
    const __bf16* Vp = Vt + (size_t)bh * HD * T_SEQ;
    char* plds = (char*)plds_all[wave];

    // Q as B-operand: col=q=lr, d = g*8+e (+32*kc)
    bf16x8 qf[2][2];
#pragma unroll
    for (int qi = 0; qi < 2; qi++)
#pragma unroll
        for (int kc = 0; kc < 2; kc++)
            qf[qi][kc] = *(const bf16x8*)(Q + (size_t)(q0 + qi * 16 + lr) * HD +
                                          kc * 32 + g * 8);

    f32x4 o[2][4] = {};
    float mrun[2] = {-1e30f, -1e30f};
    float lrun[2] = {0.f, 0.f};

    for (int kk = 0; kk < T_SEQ; kk += 64) {
        f32x4 s[4][2] = {};   // [ki][qi], S^T fragments
#pragma unroll
        for (int kc = 0; kc < 2; kc++) {
            bf16x8 kf[4];
#pragma unroll
            for (int ki = 0; ki < 4; ki++)
                kf[ki] = *(const bf16x8*)(Kp + (size_t)(kk + ki * 16 + lr) * HD +
                                          kc * 32 + g * 8);
#pragma unroll
            for (int ki = 0; ki < 4; ki++)
#pragma unroll
                for (int qi = 0; qi < 2; qi++)
                    s[ki][qi] = __builtin_amdgcn_mfma_f32_16x16x32_bf16(
                        kf[ki], qf[qi][kc], s[ki][qi], 0, 0, 0);
        }
        float facT[2][4];
#pragma unroll
        for (int qi = 0; qi < 2; qi++) {
            // in-lane max over this lane's 16 S values
            float t0 = fmaxf(fmaxf(s[0][qi][0], s[0][qi][1]), fmaxf(s[0][qi][2], s[0][qi][3]));
            float t1 = fmaxf(fmaxf(s[1][qi][0], s[1][qi][1]), fmaxf(s[1][qi][2], s[1][qi][3]));
            float t2 = fmaxf(fmaxf(s[2][qi][0], s[2][qi][1]), fmaxf(s[2][qi][2], s[2][qi][3]));
            float t3 = fmaxf(fmaxf(s[3][qi][0], s[3][qi][1]), fmaxf(s[3][qi][2], s[3][qi][3]));
            float tv = fmaxf(fmaxf(t0, t1), fmaxf(t2, t3));
            tv = fmaxf(tv, __shfl_xor(tv, 16, 64));
            tv = fmaxf(tv, __shfl_xor(tv, 32, 64));
            float mnew = fmaxf(mrun[qi], tv);
            float fac = __builtin_amdgcn_exp2f(mrun[qi] - mnew);
            mrun[qi] = mnew;
            int qrow = qi * 16 + lr;
            float ts = 0.f;
#pragma unroll
            for (int ki = 0; ki < 4; ki++) {
                float p0 = __builtin_amdgcn_exp2f(s[ki][qi][0] - mnew);
                float p1 = __builtin_amdgcn_exp2f(s[ki][qi][1] - mnew);
                float p2 = __builtin_amdgcn_exp2f(s[ki][qi][2] - mnew);
                float p3 = __builtin_amdgcn_exp2f(s[ki][qi][3] - mnew);
                ts += (p0 + p1) + (p2 + p3);
                bf16x4 pk;
                pk[0] = (__bf16)p0; pk[1] = (__bf16)p1;
                pk[2] = (__bf16)p2; pk[3] = (__bf16)p3;
                *(bf16x4*)(plds + qrow * 128 + ((ki * 32 + g * 8) ^ ((qrow & 7) << 4))) = pk;
            }
            ts += __shfl_xor(ts, 16, 64);
            ts += __shfl_xor(ts, 32, 64);
            lrun[qi] = lrun[qi] * fac + ts;
            // transpose fac into O-fragment row layout (q = qi*16 + g*4 + r)
#pragma unroll
            for (int r = 0; r < 4; r++)
                facT[qi][r] = __shfl(fac, g * 4 + r, 64);
        }
#pragma unroll
        for (int mi = 0; mi < 2; mi++)
#pragma unroll
            for (int nf = 0; nf < 4; nf++)
#pragma unroll
                for (int r = 0; r < 4; r++)
                    o[mi][nf][r] *= facT[mi][r];
        // PV: A = P from LDS (row=q=lr, k-slot), B = V via Vt (contiguous 16B)
#pragma unroll
        for (int kc = 0; kc < 2; kc++) {
            bf16x8 pf[2], vf[4];
#pragma unroll
            for (int mi = 0; mi < 2; mi++) {
                int row = mi * 16 + lr;
                pf[mi] = *(const bf16x8*)(plds + row * 128 +
                                          ((kc * 64 + g * 16) ^ ((row & 7) << 4)));
            }
#pragma unroll
            for (int nf = 0; nf < 4; nf++)
                vf[nf] = *(const bf16x8*)(Vp + (size_t)(nf * 16 + lr) * T_SEQ +
                                          kk + kc * 32 + g * 8);
#pragma unroll
            for (int mi = 0; mi < 2; mi++)
#pragma unroll
                for (int nf = 0; nf < 4; nf++)
                    o[mi][nf] = __builtin_amdgcn_mfma_f32_16x16x32_bf16(
                        pf[mi], vf[nf], o[mi][nf], 0, 0, 0);
        }
    }

    const int bb = bh >> 4, hh = bh & 15;
    float invT[2][4];
#pragma unroll
    for (int mi = 0; mi < 2; mi++)
#pragma unroll
        for (int r = 0; r < 4; r++)
            invT[mi][r] = 1.f / __shfl(lrun[mi], g * 4 + r, 64);
#pragma unroll
    for (int mi = 0; mi < 2; mi++)
#pragma unroll
        for (int r = 0; r < 4; r++) {
            int t = q0 + mi * 16 + g * 4 + r;
#pragma unroll
            for (int nf = 0; nf < 4; nf++) {
                int d = nf * 16 + lr;
                aout[((size_t)(bb * T_SEQ + t)) * D_MODEL + hh * HD + d] =
                    (__bf16)(o[mi][nf][r] * invT[mi][r]);
            }
        }
}

// ---------------------------------------------------------------------------
extern "C" void kernel_launch(void* const* d_in, const int* in_sizes, int n_in,
                              void* d_out, int out_size, void* d_ws, size_t ws_size,
                              hipStream_t stream) {
    const float* x      = (const float*)d_in[0];
    const float* norm_w = (const float*)d_in[1];
    const float* w_qkv  = (const float*)d_in[2];
    const float* w_out  = (const float*)d_in[3];
    float* out = (float*)d_out;
    char* ws = (char*)d_ws;

    // workspace layout (41 MB)
    __bf16* hbuf  = (__bf16*)(ws);                              // 8 MB (reused as attn_out)
    __bf16* wqkvT = (__bf16*)(ws + ((size_t)8  << 20));         // 6 MB
    __bf16* woutT = (__bf16*)(ws + ((size_t)14 << 20));         // 2 MB
    float2* tab   = (float2*)(ws + ((size_t)16 << 20));         // 0.5 MB
    __bf16* Qr    = (__bf16*)(ws + ((size_t)17 << 20));         // 8 MB
    __bf16* Kr    = (__bf16*)(ws + ((size_t)25 << 20));         // 8 MB
    __bf16* Vt    = (__bf16*)(ws + ((size_t)33 << 20));         // 8 MB

    k_rope_table<<<dim3(256), dim3(256), 0, stream>>>(tab);
    k_rmsnorm<<<dim3(4096), dim3(256), 0, stream>>>(x, norm_w, hbuf);
    k_transpose_cast<<<dim3(96, 32), dim3(256), 0, stream>>>(w_qkv, wqkvT, 1024, 3072);
    k_transpose_cast<<<dim3(32, 32), dim3(256), 0, stream>>>(w_out, woutT, 1024, 1024);
    k_gemm<0><<<dim3(24, 32), dim3(256), 0, stream>>>(hbuf, wqkvT, 1024, tab,
                                                      Qr, Kr, Vt, nullptr, nullptr);
    k_attn<<<dim3(16, 32), dim3(256), 0, stream>>>(Qr, Kr, Vt, hbuf);
    k_gemm<1><<<dim3(8, 32), dim3(256), 0, stream>>>(hbuf, woutT, 1024, nullptr,
                                                     nullptr, nullptr, nullptr, x, out);
}